// Round 1
// baseline (926.338 us; speedup 1.0000x reference)
//
#include <hip/hip_runtime.h>
#include <math.h>

// ---------------- linear: xl = x@wl+bl, xr = x@wr+br ----------------
#define LROWS 8
__global__ __launch_bounds__(256) void linear_kernel(
    const float* __restrict__ x, const float* __restrict__ wl, const float* __restrict__ bl,
    const float* __restrict__ wr, const float* __restrict__ br,
    float* __restrict__ xl, float* __restrict__ xr, int N)
{
    __shared__ float4 sx[LROWS][32];  // 8 rows x 128 floats
    int t = threadIdx.x;
    int r0 = blockIdx.x * LROWS;
    int nr = min(LROWS, N - r0);
    {
        const float4* xi = (const float4*)(x + (size_t)r0 * 128);
        if (t < nr * 32) ((float4*)sx)[t] = xi[t];
    }
    __syncthreads();
    int mat = t >> 7, col = t & 127;
    const float* w = mat ? wr : wl;
    float acc[LROWS];
#pragma unroll
    for (int r = 0; r < LROWS; ++r) acc[r] = 0.f;
    for (int i = 0; i < 128; i += 4) {
        float w0 = w[(i + 0) * 128 + col];
        float w1 = w[(i + 1) * 128 + col];
        float w2 = w[(i + 2) * 128 + col];
        float w3 = w[(i + 3) * 128 + col];
#pragma unroll
        for (int r = 0; r < LROWS; ++r) {
            float4 xv = sx[r][i >> 2];
            acc[r] = fmaf(xv.x, w0, acc[r]);
            acc[r] = fmaf(xv.y, w1, acc[r]);
            acc[r] = fmaf(xv.z, w2, acc[r]);
            acc[r] = fmaf(xv.w, w3, acc[r]);
        }
    }
    float b = mat ? br[col] : bl[col];
    float* o = mat ? xr : xl;
    for (int r = 0; r < nr; ++r) o[(size_t)(r0 + r) * 128 + col] = acc[r] + b;
}

// ---------------- gate: softmax(x @ gw + gb) , one wave per node ----------------
__global__ __launch_bounds__(256) void gate_kernel(
    const float* __restrict__ x, const float* __restrict__ gw, const float* __restrict__ gb,
    float* __restrict__ gate4, int N)
{
    int wid = (int)((blockIdx.x * (size_t)blockDim.x + threadIdx.x) >> 6);
    int lane = threadIdx.x & 63;
    if (wid >= N) return;
    float2 xv = *(const float2*)(x + (size_t)wid * 128 + 2 * lane);
    int i0 = 2 * lane, i1 = 2 * lane + 1;
    float s0 = xv.x * gw[i0 * 3 + 0] + xv.y * gw[i1 * 3 + 0];
    float s1 = xv.x * gw[i0 * 3 + 1] + xv.y * gw[i1 * 3 + 1];
    float s2 = xv.x * gw[i0 * 3 + 2] + xv.y * gw[i1 * 3 + 2];
    for (int off = 1; off < 64; off <<= 1) {
        s0 += __shfl_xor(s0, off);
        s1 += __shfl_xor(s1, off);
        s2 += __shfl_xor(s2, off);
    }
    s0 += gb[0]; s1 += gb[1]; s2 += gb[2];
    float mx = fmaxf(s0, fmaxf(s1, s2));
    float e0 = __expf(s0 - mx), e1 = __expf(s1 - mx), e2 = __expf(s2 - mx);
    float invd = 1.f / (e0 + e1 + e2);
    if (lane == 0) {
        float* g = gate4 + (size_t)wid * 4;
        g[0] = e0 * invd; g[1] = e1 * invd; g[2] = e2 * invd; g[3] = 0.f;
    }
}

// ---------------- CSR build ----------------
__global__ void count_kernel(const int* __restrict__ dst, int E, int* __restrict__ counts) {
    int e = blockIdx.x * blockDim.x + threadIdx.x;
    if (e < E) atomicAdd(&counts[dst[e]], 1);
}

__global__ __launch_bounds__(1024) void scan_kernel(const int* __restrict__ counts,
                                                    int* __restrict__ offsets, int N, int addloop) {
    __shared__ int sums[1024];
    int t = threadIdx.x;
    int per = (N + 1023) / 1024;
    int b = t * per, e2 = min(N, b + per);
    int s = 0;
    for (int i = b; i < e2; ++i) s += counts[i] + addloop;
    sums[t] = s;
    __syncthreads();
    for (int off = 1; off < 1024; off <<= 1) {
        int v = (t >= off) ? sums[t - off] : 0;
        __syncthreads();
        sums[t] += v;
        __syncthreads();
    }
    int run = (t > 0) ? sums[t - 1] : 0;
    for (int i = b; i < e2; ++i) { offsets[i] = run; run += counts[i] + addloop; }
    if (t == 1023) offsets[N] = sums[1023];
}

__global__ void init_cursor(const int* __restrict__ offsets, int* __restrict__ cursor,
                            int* __restrict__ csr_src, int N, int addloop) {
    int n = blockIdx.x * blockDim.x + threadIdx.x;
    if (n < N) {
        int o = offsets[n];
        if (addloop) { csr_src[o] = n; cursor[n] = o + 1; }
        else cursor[n] = o;
    }
}

__global__ void scatter_kernel(const int* __restrict__ src, const int* __restrict__ dst, int E,
                               int* __restrict__ cursor, int* __restrict__ csr_src) {
    int e = blockIdx.x * blockDim.x + threadIdx.x;
    if (e < E) {
        int p = atomicAdd(&cursor[dst[e]], 1);
        csr_src[p] = src[e];
    }
}

// ---------------- node kernel: one wave per dst node, online softmax ----------------
// lane l holds vector elements 2l, 2l+1 of the 128-elem (H=4,C=32) feature.
// head = lane>>4 (16 lanes per head); c = 2*(lane&15).
__global__ __launch_bounds__(256) void node_kernel(
    const float* __restrict__ xl, const float* __restrict__ xr,
    const int* __restrict__ csr_src, const int* __restrict__ offsets,
    const float* __restrict__ att,   // [128] this hop
    const float* __restrict__ bias,  // [32]  this hop
    const float* __restrict__ gate4, // [N*4]
    float* __restrict__ out,         // [N*32]
    int N, int hop)
{
    int wid = (int)((blockIdx.x * (size_t)blockDim.x + threadIdx.x) >> 6);
    int lane = threadIdx.x & 63;
    if (wid >= N) return;
    int n = wid;
    int beg = offsets[n], end = offsets[n + 1];

    float2 a2 = *(const float2*)(att + 2 * lane);
    float2 r2 = *(const float2*)(xr + (size_t)n * 128 + 2 * lane);

    float m = -INFINITY, d = 0.f;
    float accx = 0.f, accy = 0.f;

    for (int e = beg; e < end; ++e) {
        int src = csr_src[e];
        float2 l2 = *(const float2*)(xl + (size_t)src * 128 + 2 * lane);
        float g0 = l2.x + r2.x, g1 = l2.y + r2.y;
        g0 = fmaxf(g0, 0.f) + 0.2f * fminf(g0, 0.f);
        g1 = fmaxf(g1, 0.f) + 0.2f * fminf(g1, 0.f);
        float p = g0 * a2.x + g1 * a2.y;
        p += __shfl_xor(p, 1);
        p += __shfl_xor(p, 2);
        p += __shfl_xor(p, 4);
        p += __shfl_xor(p, 8);      // p = logit for head = lane>>4
        float nm = fmaxf(m, p);
        float s = __expf(m - nm);   // ==1 when max unchanged; ==0 on first edge (m=-inf)
        float w = __expf(p - nm);
        d = d * s + w;
        accx = accx * s + w * l2.x;
        accy = accy * s + w * l2.y;
        m = nm;
    }

    float inv = (d > 0.f) ? (1.0f / d) : 0.f;  // deg==0 -> msg = bias
    float px = accx * inv, py = accy * inv;
    // sum the 4 heads (lanes l, l+16, l+32, l+48 share c)
    px += __shfl_xor(px, 16); py += __shfl_xor(py, 16);
    px += __shfl_xor(px, 32); py += __shfl_xor(py, 32);

    if (lane < 16) {
        int c = 2 * lane;
        float2 b2 = *(const float2*)(bias + c);
        float msg0 = px * 0.25f + b2.x;
        float msg1 = py * 0.25f + b2.y;
        float gwt = gate4[(size_t)n * 4 + hop];
        float2* op = (float2*)(out + (size_t)n * 32 + c);
        if (hop == 0) {
            *op = make_float2(gwt * msg0, gwt * msg1);
        } else {
            float2 cur = *op;
            *op = make_float2(cur.x + gwt * msg0, cur.y + gwt * msg1);
        }
    }
}

// ---------------- launch ----------------
extern "C" void kernel_launch(void* const* d_in, const int* in_sizes, int n_in,
                              void* d_out, int out_size, void* d_ws, size_t ws_size,
                              hipStream_t stream) {
    const float* x  = (const float*)d_in[0];
    const int* ei[3] = { (const int*)d_in[1], (const int*)d_in[2], (const int*)d_in[3] };
    const float* wl = (const float*)d_in[4];
    const float* bl = (const float*)d_in[5];
    const float* wr = (const float*)d_in[6];
    const float* br = (const float*)d_in[7];
    const float* att = (const float*)d_in[8];
    const float* cb  = (const float*)d_in[9];
    const float* gw  = (const float*)d_in[10];
    const float* gb  = (const float*)d_in[11];

    int N = in_sizes[0] / 128;
    int E = in_sizes[1] / 2;
    float* out = (float*)d_out;

    char* ws = (char*)d_ws;
    float* xl    = (float*)ws; ws += (size_t)N * 128 * 4;
    float* xr    = (float*)ws; ws += (size_t)N * 128 * 4;
    float* gate4 = (float*)ws; ws += (size_t)N * 4 * 4;
    int* offsets = (int*)ws;   ws += (size_t)(N + 1) * 4;
    int* counts  = (int*)ws;   ws += (size_t)N * 4;
    int* cursor  = (int*)ws;   ws += (size_t)N * 4;
    int* csr_src = (int*)ws;   ws += (size_t)(E + N) * 4;

    linear_kernel<<<(N + LROWS - 1) / LROWS, 256, 0, stream>>>(x, wl, bl, wr, br, xl, xr, N);
    gate_kernel<<<(int)(((size_t)N * 64 + 255) / 256), 256, 0, stream>>>(x, gw, gb, gate4, N);

    for (int k = 0; k < 3; ++k) {
        int addloop = (k == 0) ? 1 : 0;
        hipMemsetAsync(counts, 0, (size_t)N * 4, stream);
        count_kernel<<<(E + 255) / 256, 256, 0, stream>>>(ei[k] + E, E, counts);
        scan_kernel<<<1, 1024, 0, stream>>>(counts, offsets, N, addloop);
        init_cursor<<<(N + 255) / 256, 256, 0, stream>>>(offsets, cursor, csr_src, N, addloop);
        scatter_kernel<<<(E + 255) / 256, 256, 0, stream>>>(ei[k], ei[k] + E, E, cursor, csr_src);
        node_kernel<<<(int)(((size_t)N * 64 + 255) / 256), 256, 0, stream>>>(
            xl, xr, csr_src, offsets, att + k * 128, cb + k * 32, gate4, out, N, k);
    }
}

// Round 2
// 638.628 us; speedup vs baseline: 1.4505x; 1.4505x over previous
//
#include <hip/hip_runtime.h>
#include <math.h>

typedef unsigned int uint32;
typedef unsigned short ushort16;

__device__ __forceinline__ ushort16 f2bf(float f) {  // RNE, no NaN handling (values are normal)
    uint32 u = __float_as_uint(f);
    u += 0x7fffu + ((u >> 16) & 1u);
    return (ushort16)(u >> 16);
}

// ---------------- linear: xl = bf16(x@wl+bl), xr = x@wr+br ----------------
#define LROWS 8
__global__ __launch_bounds__(256) void linear_kernel(
    const float* __restrict__ x, const float* __restrict__ wl, const float* __restrict__ bl,
    const float* __restrict__ wr, const float* __restrict__ br,
    ushort16* __restrict__ xl, float* __restrict__ xr, int N)
{
    __shared__ float4 sx[LROWS][32];
    int t = threadIdx.x;
    int r0 = blockIdx.x * LROWS;
    int nr = min(LROWS, N - r0);
    {
        const float4* xi = (const float4*)(x + (size_t)r0 * 128);
        if (t < nr * 32) ((float4*)sx)[t] = xi[t];
    }
    __syncthreads();
    int mat = t >> 7, col = t & 127;
    const float* w = mat ? wr : wl;
    float acc[LROWS];
#pragma unroll
    for (int r = 0; r < LROWS; ++r) acc[r] = 0.f;
    for (int i = 0; i < 128; i += 4) {
        float w0 = w[(i + 0) * 128 + col];
        float w1 = w[(i + 1) * 128 + col];
        float w2 = w[(i + 2) * 128 + col];
        float w3 = w[(i + 3) * 128 + col];
#pragma unroll
        for (int r = 0; r < LROWS; ++r) {
            float4 xv = sx[r][i >> 2];
            acc[r] = fmaf(xv.x, w0, acc[r]);
            acc[r] = fmaf(xv.y, w1, acc[r]);
            acc[r] = fmaf(xv.z, w2, acc[r]);
            acc[r] = fmaf(xv.w, w3, acc[r]);
        }
    }
    if (mat) {
        float b = br[col];
        for (int r = 0; r < nr; ++r) xr[(size_t)(r0 + r) * 128 + col] = acc[r] + b;
    } else {
        float b = bl[col];
        for (int r = 0; r < nr; ++r) xl[(size_t)(r0 + r) * 128 + col] = f2bf(acc[r] + b);
    }
}

// ---------------- gate: softmax(x @ gw + gb), one wave per node ----------------
__global__ __launch_bounds__(256) void gate_kernel(
    const float* __restrict__ x, const float* __restrict__ gw, const float* __restrict__ gb,
    float* __restrict__ gate4, int N)
{
    int wid = (int)((blockIdx.x * (size_t)blockDim.x + threadIdx.x) >> 6);
    int lane = threadIdx.x & 63;
    if (wid >= N) return;
    float2 xv = *(const float2*)(x + (size_t)wid * 128 + 2 * lane);
    int i0 = 2 * lane, i1 = 2 * lane + 1;
    float s0 = xv.x * gw[i0 * 3 + 0] + xv.y * gw[i1 * 3 + 0];
    float s1 = xv.x * gw[i0 * 3 + 1] + xv.y * gw[i1 * 3 + 1];
    float s2 = xv.x * gw[i0 * 3 + 2] + xv.y * gw[i1 * 3 + 2];
    for (int off = 1; off < 64; off <<= 1) {
        s0 += __shfl_xor(s0, off);
        s1 += __shfl_xor(s1, off);
        s2 += __shfl_xor(s2, off);
    }
    s0 += gb[0]; s1 += gb[1]; s2 += gb[2];
    float mx = fmaxf(s0, fmaxf(s1, s2));
    float e0 = __expf(s0 - mx), e1 = __expf(s1 - mx), e2 = __expf(s2 - mx);
    float invd = 1.f / (e0 + e1 + e2);
    if (lane == 0) {
        float* g = gate4 + (size_t)wid * 4;
        g[0] = e0 * invd; g[1] = e1 * invd; g[2] = e2 * invd; g[3] = 0.f;
    }
}

// ---------------- CSR build, all 3 hops at once ----------------
// Synthetic edges [3E, 3E+N) are hop-0 self-loops (src=dst=n).
__global__ void count_all(const int* __restrict__ e0, const int* __restrict__ e1,
                          const int* __restrict__ e2, int E, int N,
                          int* __restrict__ counts, int T) {
    int t = blockIdx.x * blockDim.x + threadIdx.x;
    if (t >= T) return;
    int hop, dst;
    if (t < E)          { hop = 0; dst = e0[E + t]; }
    else if (t < 2 * E) { hop = 1; dst = e1[E + t - E]; }
    else if (t < 3 * E) { hop = 2; dst = e2[E + t - 2 * E]; }
    else                { hop = 0; dst = t - 3 * E; }
    atomicAdd(counts + (size_t)hop * N + dst, 1);
}

__global__ __launch_bounds__(1024) void scan1(const int* __restrict__ counts, int M,
                                              int* __restrict__ offsets, int* __restrict__ partials) {
    __shared__ int s[1024];
    int t = threadIdx.x;
    int i = blockIdx.x * 1024 + t;
    int v = (i < M) ? counts[i] : 0;
    s[t] = v;
    __syncthreads();
    for (int o = 1; o < 1024; o <<= 1) {
        int u = (t >= o) ? s[t - o] : 0;
        __syncthreads();
        s[t] += u;
        __syncthreads();
    }
    if (i < M) offsets[i] = s[t] - v;              // intra-block exclusive
    if (t == 1023) partials[blockIdx.x] = s[1023]; // block total
}

__global__ __launch_bounds__(1024) void scan2(int* __restrict__ partials, int G,
                                              int* __restrict__ offsets, int M) {
    __shared__ int s[1024];
    int t = threadIdx.x;
    int v = (t < G) ? partials[t] : 0;
    s[t] = v;
    __syncthreads();
    for (int o = 1; o < 1024; o <<= 1) {
        int u = (t >= o) ? s[t - o] : 0;
        __syncthreads();
        s[t] += u;
        __syncthreads();
    }
    if (t < G) partials[t] = s[t] - v;  // exclusive block prefix
    if (t == 0) offsets[M] = s[1023];   // grand total
}

__global__ __launch_bounds__(1024) void scan3(int* __restrict__ offsets, int* __restrict__ cursor,
                                              const int* __restrict__ partials, int M) {
    int i = blockIdx.x * 1024 + threadIdx.x;
    if (i < M) {
        int v = offsets[i] + partials[blockIdx.x];
        offsets[i] = v;
        cursor[i] = v;
    }
}

__global__ void scatter_all(const int* __restrict__ e0, const int* __restrict__ e1,
                            const int* __restrict__ e2, int E, int N,
                            int* __restrict__ cursor, int* __restrict__ csr_src, int T) {
    int t = blockIdx.x * blockDim.x + threadIdx.x;
    if (t >= T) return;
    int hop, src, dst;
    if (t < E)          { hop = 0; src = e0[t];         dst = e0[E + t]; }
    else if (t < 2 * E) { hop = 1; src = e1[t - E];     dst = e1[E + t - E]; }
    else if (t < 3 * E) { hop = 2; src = e2[t - 2 * E]; dst = e2[E + t - 2 * E]; }
    else                { hop = 0; src = t - 3 * E;     dst = src; }
    int p = atomicAdd(cursor + (size_t)hop * N + dst, 1);
    csr_src[p] = src;
}

// ---------------- node kernel: one wave per dst node, all 3 hops, online softmax ----------------
// lane l holds feature elements 2l, 2l+1 (bf16x2 packed for xl); head = lane>>4.
__global__ __launch_bounds__(256) void node_all(
    const uint32* __restrict__ xl,   // [N*64] packed bf16x2
    const float* __restrict__ xr,    // [N*128]
    const int* __restrict__ csr_src, const int* __restrict__ offsets,  // [3N+1]
    const float* __restrict__ att,   // [3*128]
    const float* __restrict__ bias,  // [3*32]
    const float* __restrict__ gate4, // [N*4]
    float* __restrict__ out,         // [N*32]
    int N)
{
    int wid = (int)((blockIdx.x * (size_t)blockDim.x + threadIdx.x) >> 6);
    int lane = threadIdx.x & 63;
    if (wid >= N) return;
    int n = wid;
    float2 r2 = *(const float2*)(xr + (size_t)n * 128 + 2 * lane);
    int c = 2 * (lane & 15);
    float resx = 0.f, resy = 0.f;

#pragma unroll
    for (int h = 0; h < 3; ++h) {
        float2 a2 = *(const float2*)(att + h * 128 + 2 * lane);
        int beg = offsets[(size_t)h * N + n], end = offsets[(size_t)h * N + n + 1];
        float m = -INFINITY, d = 0.f, accx = 0.f, accy = 0.f;
        if (beg < end) {
            int src = csr_src[beg];
            uint32 lv = xl[(size_t)src * 64 + lane];  // prefetch first
            for (int e = beg; e < end; ++e) {
                uint32 cv = lv;
                if (e + 1 < end) {                     // prefetch next gather
                    int sn = csr_src[e + 1];
                    lv = xl[(size_t)sn * 64 + lane];
                }
                float lx = __uint_as_float(cv << 16);
                float ly = __uint_as_float(cv & 0xffff0000u);
                float g0 = lx + r2.x, g1 = ly + r2.y;
                g0 = fmaxf(g0, 0.f) + 0.2f * fminf(g0, 0.f);
                g1 = fmaxf(g1, 0.f) + 0.2f * fminf(g1, 0.f);
                float p = g0 * a2.x + g1 * a2.y;
                p += __shfl_xor(p, 1);
                p += __shfl_xor(p, 2);
                p += __shfl_xor(p, 4);
                p += __shfl_xor(p, 8);     // head logit
                float nm = fmaxf(m, p);
                float sc = __expf(m - nm); // 0 on first edge, 1 if max unchanged
                float w = __expf(p - nm);
                d = d * sc + w;
                accx = accx * sc + w * lx;
                accy = accy * sc + w * ly;
                m = nm;
            }
        }
        float inv = (d > 0.f) ? (1.0f / d) : 0.f;  // deg==0 -> msg = bias
        float px = accx * inv, py = accy * inv;
        px += __shfl_xor(px, 16); py += __shfl_xor(py, 16);
        px += __shfl_xor(px, 32); py += __shfl_xor(py, 32);
        float2 b2 = *(const float2*)(bias + h * 32 + c);
        float g = gate4[(size_t)n * 4 + h];
        resx += g * (px * 0.25f + b2.x);
        resy += g * (py * 0.25f + b2.y);
    }
    if (lane < 16) *(float2*)(out + (size_t)n * 32 + c) = make_float2(resx, resy);
}

// ---------------- launch ----------------
extern "C" void kernel_launch(void* const* d_in, const int* in_sizes, int n_in,
                              void* d_out, int out_size, void* d_ws, size_t ws_size,
                              hipStream_t stream) {
    const float* x  = (const float*)d_in[0];
    const int* e0 = (const int*)d_in[1];
    const int* e1 = (const int*)d_in[2];
    const int* e2 = (const int*)d_in[3];
    const float* wl = (const float*)d_in[4];
    const float* bl = (const float*)d_in[5];
    const float* wr = (const float*)d_in[6];
    const float* br = (const float*)d_in[7];
    const float* att = (const float*)d_in[8];
    const float* cb  = (const float*)d_in[9];
    const float* gw  = (const float*)d_in[10];
    const float* gb  = (const float*)d_in[11];

    int N = in_sizes[0] / 128;
    int E = in_sizes[1] / 2;
    float* out = (float*)d_out;

    char* ws = (char*)d_ws;
    ushort16* xl = (ushort16*)ws; ws += (size_t)N * 128 * 2;
    float* xr    = (float*)ws;    ws += (size_t)N * 128 * 4;
    float* gate4 = (float*)ws;    ws += (size_t)N * 4 * 4;
    int M = 3 * N;
    int* offsets  = (int*)ws; ws += (size_t)(M + 1) * 4;
    int* counts   = (int*)ws; ws += (size_t)M * 4;
    int* cursor   = (int*)ws; ws += (size_t)M * 4;
    int* partials = (int*)ws; ws += 4096;
    int* csr_src  = (int*)ws; ws += (size_t)(3 * E + N) * 4;

    linear_kernel<<<(N + LROWS - 1) / LROWS, 256, 0, stream>>>(x, wl, bl, wr, br, xl, xr, N);
    gate_kernel<<<(int)(((size_t)N * 64 + 255) / 256), 256, 0, stream>>>(x, gw, gb, gate4, N);

    hipMemsetAsync(counts, 0, (size_t)M * 4, stream);
    int T = 3 * E + N;
    count_all<<<(T + 255) / 256, 256, 0, stream>>>(e0, e1, e2, E, N, counts, T);
    int G = (M + 1023) / 1024;
    scan1<<<G, 1024, 0, stream>>>(counts, M, offsets, partials);
    scan2<<<1, 1024, 0, stream>>>(partials, G, offsets, M);
    scan3<<<G, 1024, 0, stream>>>(offsets, cursor, partials, M);
    scatter_all<<<(T + 255) / 256, 256, 0, stream>>>(e0, e1, e2, E, N, cursor, csr_src, T);

    node_all<<<(int)(((size_t)N * 64 + 255) / 256), 256, 0, stream>>>(
        (const uint32*)xl, xr, csr_src, offsets, att, cb, gate4, out, N);
}

// Round 3
// 380.100 us; speedup vs baseline: 2.4371x; 1.6802x over previous
//
#include <hip/hip_runtime.h>
#include <math.h>

typedef unsigned int uint32;
typedef unsigned short u16;

#if __has_builtin(__builtin_amdgcn_exp2f)
#define EXP2F(x) __builtin_amdgcn_exp2f(x)
#else
#define EXP2F(x) exp2f(x)
#endif

__device__ __forceinline__ u16 f2bf(float f) {  // RNE
    uint32 u = __float_as_uint(f);
    u += 0x7fffu + ((u >> 16) & 1u);
    return (u16)(u >> 16);
}

// ---------------- linear + gate: xl = bf16(x@wl+bl), xr = x@wr+br, gate = softmax(x@gw+gb) ----
#define LROWS 8
__global__ __launch_bounds__(256) void linear_kernel(
    const float* __restrict__ x, const float* __restrict__ wl, const float* __restrict__ bl,
    const float* __restrict__ wr, const float* __restrict__ br,
    const float* __restrict__ gw, const float* __restrict__ gb,
    u16* __restrict__ xl, float* __restrict__ xr, float* __restrict__ gate4, int N)
{
    __shared__ float4 sx[LROWS][32];
    __shared__ float gbuf[LROWS][3];
    int t = threadIdx.x;
    int r0 = blockIdx.x * LROWS;
    int nr = min(LROWS, N - r0);
    {
        const float4* xi = (const float4*)(x + (size_t)r0 * 128);
        if (t < nr * 32) ((float4*)sx)[t] = xi[t];
    }
    __syncthreads();
    int mat = t >> 7, col = t & 127;
    const float* w = mat ? wr : wl;
    float acc[LROWS];
#pragma unroll
    for (int r = 0; r < LROWS; ++r) acc[r] = 0.f;
    for (int i = 0; i < 128; i += 4) {
        float w0 = w[(i + 0) * 128 + col];
        float w1 = w[(i + 1) * 128 + col];
        float w2 = w[(i + 2) * 128 + col];
        float w3 = w[(i + 3) * 128 + col];
#pragma unroll
        for (int r = 0; r < LROWS; ++r) {
            float4 xv = sx[r][i >> 2];
            acc[r] = fmaf(xv.x, w0, acc[r]);
            acc[r] = fmaf(xv.y, w1, acc[r]);
            acc[r] = fmaf(xv.z, w2, acc[r]);
            acc[r] = fmaf(xv.w, w3, acc[r]);
        }
    }
    if (mat) {
        float b = br[col];
        for (int r = 0; r < nr; ++r) xr[(size_t)(r0 + r) * 128 + col] = acc[r] + b;
    } else {
        float b = bl[col];
        for (int r = 0; r < nr; ++r) xl[(size_t)(r0 + r) * 128 + col] = f2bf(acc[r] + b);
    }
    // gate: 24 threads each do one (row, k) 128-dot from LDS
    if (t < nr * 3) {
        int r = t / 3, k = t - 3 * r;
        float s = 0.f;
        const float4* xrow = sx[r];
#pragma unroll 4
        for (int i = 0; i < 32; ++i) {
            float4 v = xrow[i];
            s += v.x * gw[(4 * i + 0) * 3 + k] + v.y * gw[(4 * i + 1) * 3 + k]
               + v.z * gw[(4 * i + 2) * 3 + k] + v.w * gw[(4 * i + 3) * 3 + k];
        }
        gbuf[r][k] = s + gb[k];
    }
    __syncthreads();
    if (t < nr) {
        float s0 = gbuf[t][0], s1 = gbuf[t][1], s2 = gbuf[t][2];
        float mx = fmaxf(s0, fmaxf(s1, s2));
        float e0 = __expf(s0 - mx), e1 = __expf(s1 - mx), e2 = __expf(s2 - mx);
        float inv = 1.f / (e0 + e1 + e2);
        *(float4*)(gate4 + (size_t)(r0 + t) * 4) = make_float4(e0 * inv, e1 * inv, e2 * inv, 0.f);
    }
}

// ---------------- CSR build, all 3 hops; synthetic edges [3E,3E+N) = hop-0 self-loops --------
__global__ void count_all(const int* __restrict__ e0, const int* __restrict__ e1,
                          const int* __restrict__ e2, int E, int N,
                          int* __restrict__ counts, u16* __restrict__ rank, int T) {
    int t = blockIdx.x * blockDim.x + threadIdx.x;
    if (t >= T) return;
    int hop, dst;
    if (t < E)          { hop = 0; dst = e0[E + t]; }
    else if (t < 2 * E) { hop = 1; dst = e1[t]; }       // e1[E + (t-E)]
    else if (t < 3 * E) { hop = 2; dst = e2[t - E]; }   // e2[E + (t-2E)]
    else                { hop = 0; dst = t - 3 * E; }
    rank[t] = (u16)atomicAdd(counts + (size_t)hop * N + dst, 1);
}

__global__ __launch_bounds__(1024) void scan1(const int* __restrict__ counts, int M,
                                              int* __restrict__ offsets, int* __restrict__ partials) {
    __shared__ int s[1024];
    int t = threadIdx.x;
    int i = blockIdx.x * 1024 + t;
    int v = (i < M) ? counts[i] : 0;
    s[t] = v;
    __syncthreads();
    for (int o = 1; o < 1024; o <<= 1) {
        int u = (t >= o) ? s[t - o] : 0;
        __syncthreads();
        s[t] += u;
        __syncthreads();
    }
    if (i < M) offsets[i] = s[t] - v;
    if (t == 1023) partials[blockIdx.x] = s[1023];
}

__global__ __launch_bounds__(1024) void scan2(int* __restrict__ partials, int G,
                                              int* __restrict__ offsets, int M) {
    __shared__ int s[1024];
    int t = threadIdx.x;
    int v = (t < G) ? partials[t] : 0;
    s[t] = v;
    __syncthreads();
    for (int o = 1; o < 1024; o <<= 1) {
        int u = (t >= o) ? s[t - o] : 0;
        __syncthreads();
        s[t] += u;
        __syncthreads();
    }
    if (t < G) partials[t] = s[t] - v;
    if (t == 0) offsets[M] = s[1023];
}

__global__ __launch_bounds__(1024) void scan3(int* __restrict__ offsets,
                                              const int* __restrict__ partials, int M) {
    int i = blockIdx.x * 1024 + threadIdx.x;
    if (i < M) offsets[i] += partials[blockIdx.x];
}

__global__ void scatter_all(const int* __restrict__ e0, const int* __restrict__ e1,
                            const int* __restrict__ e2, int E, int N,
                            const int* __restrict__ offsets, const u16* __restrict__ rank,
                            int* __restrict__ csr_src, int T) {
    int t = blockIdx.x * blockDim.x + threadIdx.x;
    if (t >= T) return;
    int hop, src, dst;
    if (t < E)          { hop = 0; src = e0[t];         dst = e0[E + t]; }
    else if (t < 2 * E) { hop = 1; src = e1[t - E];     dst = e1[t]; }
    else if (t < 3 * E) { hop = 2; src = e2[t - 2 * E]; dst = e2[t - E]; }
    else                { hop = 0; src = t - 3 * E;     dst = src; }
    int p = offsets[(size_t)hop * N + dst] + (int)rank[t];
    csr_src[p] = src;
}

// ---------------- node kernel: one wave per dst node, 2 edges/iter, no-max softmax ----------
// half = lane>>5 picks edge A/B; l5 = lane&31 covers 4 features f=4*l5.. ; head = l5>>3.
__global__ __launch_bounds__(256) void node_all(
    const uint32* __restrict__ xl,   // [N*64] packed bf16x2 (view as uint2[N*32])
    const float* __restrict__ xr,    // [N*128]
    const int* __restrict__ csr_src, const int* __restrict__ offsets,  // [3N+1]
    const float* __restrict__ att,   // [3*128]
    const float* __restrict__ bias,  // [3*32]
    const float* __restrict__ gate4, // [N*4]
    float* __restrict__ out,         // [N*32]
    int N)
{
    const float LOG2E = 1.44269504088896f;
    int wid = (int)((blockIdx.x * (size_t)blockDim.x + threadIdx.x) >> 6);
    int lane = threadIdx.x & 63;
    if (wid >= N) return;
    int n = wid;
    int half = lane >> 5, l5 = lane & 31;
    const uint2* xlv = (const uint2*)xl;

    float4 r4 = ((const float4*)(xr + (size_t)n * 128))[l5];
    float res0 = 0.f, res1 = 0.f, res2 = 0.f, res3 = 0.f;

#pragma unroll
    for (int h = 0; h < 3; ++h) {
        float4 a4 = ((const float4*)(att + h * 128))[l5];
        a4.x *= LOG2E; a4.y *= LOG2E; a4.z *= LOG2E; a4.w *= LOG2E;
        int beg = offsets[(size_t)h * N + n], end = offsets[(size_t)h * N + n + 1];
        float d = 0.f, acc0 = 0.f, acc1 = 0.f, acc2 = 0.f, acc3 = 0.f;
        if (beg < end) {
            uint2 lv;
            {
                int i0 = min(beg + half, end - 1);
                int s0 = csr_src[i0];
                lv = xlv[(size_t)s0 * 32 + l5];
            }
            for (int e = beg; e < end; e += 2) {
                uint2 cv = lv;
                bool valid = (e + half) < end;
                if (e + 2 < end) {
                    int ni = min(e + 2 + half, end - 1);
                    int ns = csr_src[ni];
                    lv = xlv[(size_t)ns * 32 + l5];
                }
                float lx0 = __uint_as_float(cv.x << 16);
                float lx1 = __uint_as_float(cv.x & 0xffff0000u);
                float lx2 = __uint_as_float(cv.y << 16);
                float lx3 = __uint_as_float(cv.y & 0xffff0000u);
                float g0 = lx0 + r4.x, g1 = lx1 + r4.y, g2 = lx2 + r4.z, g3 = lx3 + r4.w;
                g0 = fmaf(0.2f, fminf(g0, 0.f), fmaxf(g0, 0.f));
                g1 = fmaf(0.2f, fminf(g1, 0.f), fmaxf(g1, 0.f));
                g2 = fmaf(0.2f, fminf(g2, 0.f), fmaxf(g2, 0.f));
                g3 = fmaf(0.2f, fminf(g3, 0.f), fmaxf(g3, 0.f));
                float p = g0 * a4.x;
                p = fmaf(g1, a4.y, p);
                p = fmaf(g2, a4.z, p);
                p = fmaf(g3, a4.w, p);
                p += __shfl_xor(p, 1);
                p += __shfl_xor(p, 2);
                p += __shfl_xor(p, 4);   // head logit * log2e
                float wv = EXP2F(p);
                wv = valid ? wv : 0.f;
                d += wv;
                acc0 = fmaf(wv, lx0, acc0);
                acc1 = fmaf(wv, lx1, acc1);
                acc2 = fmaf(wv, lx2, acc2);
                acc3 = fmaf(wv, lx3, acc3);
            }
        }
        // combine edge halves
        d += __shfl_xor(d, 32);
        acc0 += __shfl_xor(acc0, 32);
        acc1 += __shfl_xor(acc1, 32);
        acc2 += __shfl_xor(acc2, 32);
        acc3 += __shfl_xor(acc3, 32);
        float inv = (d > 0.f) ? (1.0f / d) : 0.f;  // deg==0 -> msg = bias
        float q0 = acc0 * inv, q1 = acc1 * inv, q2 = acc2 * inv, q3 = acc3 * inv;
        // sum over 4 heads (lane bits 3,4 of l5)
        q0 += __shfl_xor(q0, 8);  q0 += __shfl_xor(q0, 16);
        q1 += __shfl_xor(q1, 8);  q1 += __shfl_xor(q1, 16);
        q2 += __shfl_xor(q2, 8);  q2 += __shfl_xor(q2, 16);
        q3 += __shfl_xor(q3, 8);  q3 += __shfl_xor(q3, 16);
        float4 b4 = ((const float4*)(bias + h * 32))[l5 & 7];
        float g = gate4[(size_t)n * 4 + h];
        res0 = fmaf(g, fmaf(q0, 0.25f, b4.x), res0);
        res1 = fmaf(g, fmaf(q1, 0.25f, b4.y), res1);
        res2 = fmaf(g, fmaf(q2, 0.25f, b4.z), res2);
        res3 = fmaf(g, fmaf(q3, 0.25f, b4.w), res3);
    }
    if (lane < 8) ((float4*)(out + (size_t)n * 32))[lane] = make_float4(res0, res1, res2, res3);
}

// ---------------- launch ----------------
extern "C" void kernel_launch(void* const* d_in, const int* in_sizes, int n_in,
                              void* d_out, int out_size, void* d_ws, size_t ws_size,
                              hipStream_t stream) {
    const float* x  = (const float*)d_in[0];
    const int* e0 = (const int*)d_in[1];
    const int* e1 = (const int*)d_in[2];
    const int* e2 = (const int*)d_in[3];
    const float* wl = (const float*)d_in[4];
    const float* bl = (const float*)d_in[5];
    const float* wr = (const float*)d_in[6];
    const float* br = (const float*)d_in[7];
    const float* att = (const float*)d_in[8];
    const float* cb  = (const float*)d_in[9];
    const float* gw  = (const float*)d_in[10];
    const float* gb  = (const float*)d_in[11];

    int N = in_sizes[0] / 128;
    int E = in_sizes[1] / 2;
    float* out = (float*)d_out;

    char* ws = (char*)d_ws;
    u16* xl      = (u16*)ws;   ws += (size_t)N * 128 * 2;
    float* xr    = (float*)ws; ws += (size_t)N * 128 * 4;
    float* gate4 = (float*)ws; ws += (size_t)N * 4 * 4;
    int M = 3 * N;
    int T = 3 * E + N;
    int* offsets  = (int*)ws; ws += (size_t)(M + 1) * 4;
    int* counts   = (int*)ws; ws += (size_t)M * 4;
    int* partials = (int*)ws; ws += 4096;
    u16* rank     = (u16*)ws; ws += (size_t)T * 2;
    int* csr_src  = (int*)ws; ws += (size_t)T * 4;

    linear_kernel<<<(N + LROWS - 1) / LROWS, 256, 0, stream>>>(
        x, wl, bl, wr, br, gw, gb, xl, xr, gate4, N);

    hipMemsetAsync(counts, 0, (size_t)M * 4, stream);
    count_all<<<(T + 255) / 256, 256, 0, stream>>>(e0, e1, e2, E, N, counts, rank, T);
    int G = (M + 1023) / 1024;
    scan1<<<G, 1024, 0, stream>>>(counts, M, offsets, partials);
    scan2<<<1, 1024, 0, stream>>>(partials, G, offsets, M);
    scan3<<<G, 1024, 0, stream>>>(offsets, partials, M);
    scatter_all<<<(T + 255) / 256, 256, 0, stream>>>(e0, e1, e2, E, N, offsets, rank, csr_src, T);

    node_all<<<(int)(((size_t)N * 64 + 255) / 256), 256, 0, stream>>>(
        (const uint32*)xl, xr, csr_src, offsets, att, cb, gate4, out, N);
}

// Round 4
// 365.220 us; speedup vs baseline: 2.5364x; 1.0407x over previous
//
#include <hip/hip_runtime.h>
#include <math.h>

typedef unsigned int uint32;
typedef unsigned short u16;

#if __has_builtin(__builtin_amdgcn_exp2f)
#define EXP2F(x) __builtin_amdgcn_exp2f(x)
#else
#define EXP2F(x) exp2f(x)
#endif

__device__ __forceinline__ u16 f2bf(float f) {  // RNE
    uint32 u = __float_as_uint(f);
    u += 0x7fffu + ((u >> 16) & 1u);
    return (u16)(u >> 16);
}
__device__ __forceinline__ float bflo(uint32 v) { return __uint_as_float(v << 16); }
__device__ __forceinline__ float bfhi(uint32 v) { return __uint_as_float(v & 0xffff0000u); }

// ---- fused: [0,LB) linear+gate blocks; [LB,..) count blocks ------------------
#define LROWS 16
__global__ __launch_bounds__(256) void fused_pre(
    const float* __restrict__ x, const float* __restrict__ wl, const float* __restrict__ bl,
    const float* __restrict__ wr, const float* __restrict__ br,
    const float* __restrict__ gw, const float* __restrict__ gb,
    u16* __restrict__ xl, float* __restrict__ xr, float* __restrict__ gate4,
    const int* __restrict__ e0, const int* __restrict__ e1, const int* __restrict__ e2,
    int* __restrict__ counts, u16* __restrict__ rank,
    int N, int E, int T, int LB)
{
    if ((int)blockIdx.x >= LB) {
        int t = ((int)blockIdx.x - LB) * 256 + (int)threadIdx.x;
        if (t < T) {
            int hop, dst;
            if (t < E)          { hop = 0; dst = e0[E + t]; }
            else if (t < 2 * E) { hop = 1; dst = e1[t]; }
            else if (t < 3 * E) { hop = 2; dst = e2[t - E]; }
            else                { hop = 0; dst = t - 3 * E; }
            rank[t] = (u16)atomicAdd(counts + (size_t)hop * N + dst, 1);
        }
        return;
    }
    __shared__ float4 sx[LROWS][32];
    __shared__ float gbuf[LROWS][3];
    int t = threadIdx.x;
    int r0 = blockIdx.x * LROWS;
    int nr = min(LROWS, N - r0);
    {
        const float4* xi = (const float4*)(x + (size_t)r0 * 128);
        for (int i = t; i < nr * 32; i += 256) ((float4*)sx)[i] = xi[i];
    }
    __syncthreads();
    int mat = t >> 7, col = t & 127;
    const float* w = mat ? wr : wl;
    float acc[LROWS];
#pragma unroll
    for (int r = 0; r < LROWS; ++r) acc[r] = 0.f;
    for (int i = 0; i < 128; i += 4) {
        float w0 = w[(i + 0) * 128 + col];
        float w1 = w[(i + 1) * 128 + col];
        float w2 = w[(i + 2) * 128 + col];
        float w3 = w[(i + 3) * 128 + col];
#pragma unroll
        for (int r = 0; r < LROWS; ++r) {
            float4 xv = sx[r][i >> 2];
            acc[r] = fmaf(xv.x, w0, acc[r]);
            acc[r] = fmaf(xv.y, w1, acc[r]);
            acc[r] = fmaf(xv.z, w2, acc[r]);
            acc[r] = fmaf(xv.w, w3, acc[r]);
        }
    }
    if (mat) {
        float b = br[col];
        for (int r = 0; r < nr; ++r) xr[(size_t)(r0 + r) * 128 + col] = acc[r] + b;
    } else {
        float b = bl[col];
        for (int r = 0; r < nr; ++r) xl[(size_t)(r0 + r) * 128 + col] = f2bf(acc[r] + b);
    }
    if (t < nr * 3) {
        int r = t / 3, k = t - 3 * r;
        float s = 0.f;
        const float4* xrow = sx[r];
#pragma unroll 4
        for (int i = 0; i < 32; ++i) {
            float4 v = xrow[i];
            s += v.x * gw[(4 * i + 0) * 3 + k] + v.y * gw[(4 * i + 1) * 3 + k]
               + v.z * gw[(4 * i + 2) * 3 + k] + v.w * gw[(4 * i + 3) * 3 + k];
        }
        gbuf[r][k] = s + gb[k];
    }
    __syncthreads();
    if (t < nr) {
        float s0 = gbuf[t][0], s1 = gbuf[t][1], s2 = gbuf[t][2];
        float mx = fmaxf(s0, fmaxf(s1, s2));
        float e0v = __expf(s0 - mx), e1v = __expf(s1 - mx), e2v = __expf(s2 - mx);
        float inv = 1.f / (e0v + e1v + e2v);
        *(float4*)(gate4 + (size_t)(r0 + t) * 4) = make_float4(e0v * inv, e1v * inv, e2v * inv, 0.f);
    }
}

// ---- scans (block prefix folded at read time; scan3 eliminated) --------------
__global__ __launch_bounds__(1024) void scan1(const int* __restrict__ counts, int M,
                                              int* __restrict__ offsets, int* __restrict__ partials) {
    __shared__ int s[1024];
    int t = threadIdx.x;
    int i = blockIdx.x * 1024 + t;
    int v = (i < M) ? counts[i] : 0;
    s[t] = v;
    __syncthreads();
    for (int o = 1; o < 1024; o <<= 1) {
        int u = (t >= o) ? s[t - o] : 0;
        __syncthreads();
        s[t] += u;
        __syncthreads();
    }
    if (i < M) offsets[i] = s[t] - v;
    if (t == 1023) partials[blockIdx.x] = s[1023];
}

__global__ __launch_bounds__(1024) void scan2(int* __restrict__ partials, int G) {
    __shared__ int s[1024];
    int t = threadIdx.x;
    int v = (t < G) ? partials[t] : 0;
    s[t] = v;
    __syncthreads();
    for (int o = 1; o < 1024; o <<= 1) {
        int u = (t >= o) ? s[t - o] : 0;
        __syncthreads();
        s[t] += u;
        __syncthreads();
    }
    if (t < G) partials[t] = s[t] - v;
}

__global__ void scatter_all(const int* __restrict__ e0, const int* __restrict__ e1,
                            const int* __restrict__ e2, int E, int N,
                            const int* __restrict__ offsets, const int* __restrict__ partials,
                            const u16* __restrict__ rank, int* __restrict__ csr_src, int T) {
    int t = blockIdx.x * blockDim.x + threadIdx.x;
    if (t >= T) return;
    int hop, src, dst;
    if (t < E)          { hop = 0; src = e0[t];         dst = e0[E + t]; }
    else if (t < 2 * E) { hop = 1; src = e1[t - E];     dst = e1[t]; }
    else if (t < 3 * E) { hop = 2; src = e2[t - 2 * E]; dst = e2[t - E]; }
    else                { hop = 0; src = t - 3 * E;     dst = src; }
    int i = hop * N + dst;
    int p = offsets[i] + partials[i >> 10] + (int)rank[t];
    csr_src[p] = src;
}

// ---- node kernel: wave per node, 4 edges/iter, 16 lanes/edge, no-max softmax --
// q = lane>>4 (edge slot), l4 = lane&15 covers features 8*l4..+7; head = l4>>2.
__global__ __launch_bounds__(256) void node_all(
    const uint4* __restrict__ xl4,   // [N*16], uint4 = 8 bf16
    const float* __restrict__ xr,    // [N*128]
    const int* __restrict__ csr_src,
    const int* __restrict__ offsets, const int* __restrict__ partials,
    const float* __restrict__ att,   // [3*128]
    const float* __restrict__ bias,  // [3*32]
    const float* __restrict__ gate4, // [N*4]
    float* __restrict__ out,         // [N*32]
    int N, int M, int T)
{
    const float L2E = 1.44269504088896f;
    int wid = (int)((blockIdx.x * (size_t)blockDim.x + threadIdx.x) >> 6);
    int lane = threadIdx.x & 63;
    if (wid >= N) return;
    int n = wid;
    int q = lane >> 4, l4 = lane & 15;

    const float4* xrr = (const float4*)(xr + (size_t)n * 128);
    float4 rA = xrr[2 * l4], rB = xrr[2 * l4 + 1];
    float rr[8] = {rA.x, rA.y, rA.z, rA.w, rB.x, rB.y, rB.z, rB.w};
    float4 gv = ((const float4*)gate4)[n];
    float res[8];
#pragma unroll
    for (int j = 0; j < 8; ++j) res[j] = 0.f;

#pragma unroll
    for (int h = 0; h < 3; ++h) {
        const float4* ap = (const float4*)(att + h * 128);
        float4 aA = ap[2 * l4], aB = ap[2 * l4 + 1];
        float aa[8] = {aA.x * L2E, aA.y * L2E, aA.z * L2E, aA.w * L2E,
                       aB.x * L2E, aB.y * L2E, aB.z * L2E, aB.w * L2E};
        int i = h * N + n;
        int beg = offsets[i] + partials[i >> 10];
        int i1 = i + 1;
        int end = (i1 == M) ? T : (offsets[i1] + partials[i1 >> 10]);
        float d = 0.f;
        float acc[8];
#pragma unroll
        for (int j = 0; j < 8; ++j) acc[j] = 0.f;
        if (beg < end) {
            int s0 = csr_src[min(beg + q, end - 1)];
            uint4 lv = xl4[(size_t)s0 * 16 + l4];
            for (int e = beg; e < end; e += 4) {
                uint4 cv = lv;
                bool valid = (e + q) < end;
                if (e + 4 < end) {
                    int ns = csr_src[min(e + 4 + q, end - 1)];
                    lv = xl4[(size_t)ns * 16 + l4];
                }
                float lx[8];
                lx[0] = bflo(cv.x); lx[1] = bfhi(cv.x);
                lx[2] = bflo(cv.y); lx[3] = bfhi(cv.y);
                lx[4] = bflo(cv.z); lx[5] = bfhi(cv.z);
                lx[6] = bflo(cv.w); lx[7] = bfhi(cv.w);
                float p = 0.f;
#pragma unroll
                for (int j = 0; j < 8; ++j) {
                    float g = lx[j] + rr[j];
                    float ga = fmaf(0.4f, fabsf(g), 0.6f * g);  // leaky = 0.6g + 0.4|g|
                    p = fmaf(ga, aa[j], p);
                }
                p += __shfl_xor(p, 1);
                p += __shfl_xor(p, 2);        // head logit * log2e
                float wv = EXP2F(p);
                wv = valid ? wv : 0.f;
                d += wv;
#pragma unroll
                for (int j = 0; j < 8; ++j) acc[j] = fmaf(wv, lx[j], acc[j]);
            }
        }
        // combine the 4 edge slots (lane bits 4,5)
        d += __shfl_xor(d, 16); d += __shfl_xor(d, 32);
#pragma unroll
        for (int j = 0; j < 8; ++j) {
            acc[j] += __shfl_xor(acc[j], 16);
            acc[j] += __shfl_xor(acc[j], 32);
        }
        float inv = (d > 0.f) ? (1.0f / d) : 0.f;  // deg==0 -> msg = bias
        const float4* bp = (const float4*)(bias + h * 32);
        float4 bA = bp[2 * (l4 & 3)], bB = bp[2 * (l4 & 3) + 1];
        float bb[8] = {bA.x, bA.y, bA.z, bA.w, bB.x, bB.y, bB.z, bB.w};
        float g = (h == 0) ? gv.x : ((h == 1) ? gv.y : gv.z);
#pragma unroll
        for (int j = 0; j < 8; ++j) {
            float qv = acc[j] * inv;
            qv += __shfl_xor(qv, 4);
            qv += __shfl_xor(qv, 8);           // sum over heads (lane bits 2,3)
            res[j] = fmaf(g, fmaf(qv, 0.25f, bb[j]), res[j]);
        }
    }
    if (lane < 4) {
        float4* op = (float4*)(out + (size_t)n * 32);
        op[2 * lane]     = make_float4(res[0], res[1], res[2], res[3]);
        op[2 * lane + 1] = make_float4(res[4], res[5], res[6], res[7]);
    }
}

// ---------------- launch ----------------
extern "C" void kernel_launch(void* const* d_in, const int* in_sizes, int n_in,
                              void* d_out, int out_size, void* d_ws, size_t ws_size,
                              hipStream_t stream) {
    const float* x  = (const float*)d_in[0];
    const int* e0 = (const int*)d_in[1];
    const int* e1 = (const int*)d_in[2];
    const int* e2 = (const int*)d_in[3];
    const float* wl = (const float*)d_in[4];
    const float* bl = (const float*)d_in[5];
    const float* wr = (const float*)d_in[6];
    const float* br = (const float*)d_in[7];
    const float* att = (const float*)d_in[8];
    const float* cb  = (const float*)d_in[9];
    const float* gw  = (const float*)d_in[10];
    const float* gb  = (const float*)d_in[11];

    int N = in_sizes[0] / 128;
    int E = in_sizes[1] / 2;
    float* out = (float*)d_out;

    char* ws = (char*)d_ws;
    u16* xl      = (u16*)ws;   ws += (size_t)N * 128 * 2;
    float* xr    = (float*)ws; ws += (size_t)N * 128 * 4;
    float* gate4 = (float*)ws; ws += (size_t)N * 4 * 4;
    int M = 3 * N;
    int T = 3 * E + N;
    int* offsets  = (int*)ws; ws += (size_t)M * 4;
    int* counts   = (int*)ws; ws += (size_t)M * 4;
    int* partials = (int*)ws; ws += 4096;
    u16* rank     = (u16*)ws; ws += (size_t)T * 2;
    int* csr_src  = (int*)ws; ws += (size_t)T * 4;

    hipMemsetAsync(counts, 0, (size_t)M * 4, stream);
    int LB = (N + LROWS - 1) / LROWS;
    int CB = (T + 255) / 256;
    fused_pre<<<LB + CB, 256, 0, stream>>>(x, wl, bl, wr, br, gw, gb, xl, xr, gate4,
                                           e0, e1, e2, counts, rank, N, E, T, LB);
    int G = (M + 1023) / 1024;
    scan1<<<G, 1024, 0, stream>>>(counts, M, offsets, partials);
    scan2<<<1, 1024, 0, stream>>>(partials, G);
    scatter_all<<<(T + 255) / 256, 256, 0, stream>>>(e0, e1, e2, E, N, offsets, partials,
                                                     rank, csr_src, T);
    node_all<<<(int)(((size_t)N * 64 + 255) / 256), 256, 0, stream>>>(
        (const uint4*)xl, xr, csr_src, offsets, partials, att, cb, gate4, out, N, M, T);
}